// Round 4
// baseline (2409.899 us; speedup 1.0000x reference)
//
#include <hip/hip_runtime.h>

// RNN scan, two roles fused in one 256-thread block per batch element:
//  A) recurrence: thread (g,cg) owns 8x8 tile of W_hh ONLY (16 float4 -> fits
//     the ~88-VGPR envelope the allocator actually grants). Per step: 2
//     ds_read_b128 (h) + 16 fmac + cndmask-free DPP butterfly + tanh.
//  B) x-projection, chunk-pipelined: thread (sl,rg) accumulates full dots of
//     xw[chunk+1][sl][8rg..8rg+7], one 8-col slice per step, streaming W_ih
//     from global (L1/L2-hit) -- no persistent W_ih registers needed. Biases
//     folded into xw. Proj work is h-independent -> hides h-read latency.
// LDS rows padded to stride 132 (2-way bank aliasing = free); h padded 12/8.

#define BATCH 256
#define SEQ   2048
#define HID   128
#define CH    16
#define NCHUNK (SEQ / CH)
#define XSTR  132

// quad_perm[1,0,3,2]=0xB1 (xor1), quad_perm[2,3,0,1]=0x4E (xor2),
// row_ror:4=0x124, row_ror:8=0x128
template <int CTRL>
__device__ __forceinline__ float dpp_movf(float x) {
    return __int_as_float(__builtin_amdgcn_mov_dpp(__float_as_int(x), CTRL, 0xF, 0xF, true));
}

__device__ __forceinline__ float tanh_fast(float x) {
    x = fminf(fmaxf(x, -12.0f), 12.0f);
    float e = __expf(2.0f * x);
    return 1.0f - __fdividef(2.0f, e + 1.0f);
}

__global__ __launch_bounds__(256)
__attribute__((amdgpu_waves_per_eu(1)))
void rnn_scan_kernel(
    const float* __restrict__ x,    // [B, S, 128]
    const float* __restrict__ Wih,  // [128, 128]
    const float* __restrict__ bih,  // [128]
    const float* __restrict__ Whh,  // [128, 128]
    const float* __restrict__ bhh,  // [128]
    float* __restrict__ out)        // [B, 128]
{
    const int b = blockIdx.x;
    const int t = threadIdx.x;
    // recurrence mapping
    const int g  = t >> 4;         // rowgroup: rows 8g..8g+7
    const int cg = t & 15;         // colgroup: cols 8cg..8cg+7
    const int colbase = cg << 3;
    // projection mapping (same bits, different meaning)
    const int sl = t & 15;         // timestep-in-chunk
    const int rg = t >> 4;         // xw rows 8rg..8rg+7

    __shared__ __align__(16) float xbuf[2][CH * XSTR];   // raw x, 2 chunks
    __shared__ __align__(16) float xwbuf[2][CH * XSTR];  // projected xw+bias
    __shared__ __align__(16) float hbuf[2][192];         // padded h

    // --- W_hh tile, butterfly-permuted rows: slot r holds row 8g + (r^p) ---
    const int p = ((cg & 1) << 2) | (cg & 2);
    float4 wh[8][2];
#pragma unroll
    for (int r = 0; r < 8; ++r) {
        const float* ph = Whh + ((g << 3) + (r ^ p)) * HID + colbase;
        wh[r][0] = *(const float4*)(ph);
        wh[r][1] = *(const float4*)(ph + 4);
    }
    const int row0 = (g << 3) + p;   // lane ends with rows row0, row0+1
    const int hw = 12 * g + p;       // padded word of row0

    // --- projection biases (b_ih + b_hh for rows 8rg..8rg+7) ---
    float bias[8];
    {
        const float4 bi0 = *(const float4*)(bih + (rg << 3));
        const float4 bi1 = *(const float4*)(bih + (rg << 3) + 4);
        const float4 bh0 = *(const float4*)(bhh + (rg << 3));
        const float4 bh1 = *(const float4*)(bhh + (rg << 3) + 4);
        bias[0] = bi0.x + bh0.x; bias[1] = bi0.y + bh0.y;
        bias[2] = bi0.z + bh0.z; bias[3] = bi0.w + bh0.w;
        bias[4] = bi1.x + bh1.x; bias[5] = bi1.y + bh1.y;
        bias[6] = bi1.z + bh1.z; bias[7] = bi1.w + bh1.w;
    }

    // staging dests: float4 q -> ts=q>>5, colword=4*(q&31), word=132*ts+colword
    const int dst0 = XSTR * (t >> 5) + ((t & 31) << 2);
    const int dst1 = dst0 + XSTR * 8;

    const float* xsrc = x + (size_t)b * (SEQ * HID);

    // --- prologue: stage chunks 0,1; zero h ---
    {
        const float4* g0 = (const float4*)xsrc;
        const float4* g1 = (const float4*)(xsrc + CH * HID);
        float4 a0 = g0[t], a1 = g0[256 + t];
        float4 c0 = g1[t], c1 = g1[256 + t];
        *(float4*)&xbuf[0][dst0] = a0;
        *(float4*)&xbuf[0][dst1] = a1;
        *(float4*)&xbuf[1][dst0] = c0;
        *(float4*)&xbuf[1][dst1] = c1;
    }
    if (t < 192) hbuf[0][t] = 0.0f;
    __syncthreads();

    // --- burst: xw for chunk 0 into xwbuf[0] ---
    float xacc[8];
#pragma unroll
    for (int r = 0; r < 8; ++r) xacc[r] = bias[r];
#pragma unroll 4
    for (int cb = 0; cb < 16; ++cb) {
        const float4 xv0 = *(const float4*)&xbuf[0][XSTR * sl + 8 * cb];
        const float4 xv1 = *(const float4*)&xbuf[0][XSTR * sl + 8 * cb + 4];
#pragma unroll
        for (int r = 0; r < 8; ++r) {
            const float* wp = Wih + ((rg << 3) + r) * HID + 8 * cb;
            const float4 w0 = *(const float4*)(wp);
            const float4 w1 = *(const float4*)(wp + 4);
            float acc = xacc[r];
            acc = fmaf(w0.x, xv0.x, acc); acc = fmaf(w0.y, xv0.y, acc);
            acc = fmaf(w0.z, xv0.z, acc); acc = fmaf(w0.w, xv0.w, acc);
            acc = fmaf(w1.x, xv1.x, acc); acc = fmaf(w1.y, xv1.y, acc);
            acc = fmaf(w1.z, xv1.z, acc); acc = fmaf(w1.w, xv1.w, acc);
            xacc[r] = acc;
        }
    }
    *(float4*)&xwbuf[0][XSTR * sl + (rg << 3)] =
        make_float4(xacc[0], xacc[1], xacc[2], xacc[3]);
    *(float4*)&xwbuf[0][XSTR * sl + (rg << 3) + 4] =
        make_float4(xacc[4], xacc[5], xacc[6], xacc[7]);
#pragma unroll
    for (int r = 0; r < 8; ++r) xacc[r] = bias[r];
    __syncthreads();

    int cur = 0;
    for (int ch = 0; ch < NCHUNK; ++ch) {
        const bool pf_proj  = (ch + 1 < NCHUNK);
        const bool pf_stage = (ch + 2 < NCHUNK);
        float4 q0, q1;
        if (pf_stage) {
            const float4* gp = (const float4*)(xsrc + (size_t)(ch + 2) * (CH * HID));
            q0 = gp[t];
            q1 = gp[256 + t];
        }
        const float* xb  = &xbuf[(ch + 1) & 1][XSTR * sl];  // proj x row
        const float* xwr = &xwbuf[ch & 1][0];
        float*       xww = &xwbuf[(ch + 1) & 1][0];
#pragma unroll 1
        for (int s = 0; s < CH; ++s) {
            // --- issue proj loads early (h-independent latency fill) ---
            float4 pxv0, pxv1, pw0[8], pw1[8];
            if (pf_proj) {
                pxv0 = *(const float4*)(xb + 8 * s);
                pxv1 = *(const float4*)(xb + 8 * s + 4);
#pragma unroll
                for (int r = 0; r < 8; ++r) {
                    const float* wp = Wih + ((rg << 3) + r) * HID + 8 * s;
                    pw0[r] = *(const float4*)(wp);
                    pw1[r] = *(const float4*)(wp + 4);
                }
            }
            // --- recurrence ---
            const float* hr = &hbuf[cur][12 * cg];
            const float4 hv0 = *(const float4*)(hr);
            const float4 hv1 = *(const float4*)(hr + 4);
            const float2 xwp = *(const float2*)(xwr + XSTR * s + row0);
            float a[8];
#pragma unroll
            for (int r = 0; r < 8; ++r) {
                float acc;
                acc = wh[r][0].x * hv0.x;
                acc = fmaf(wh[r][0].y, hv0.y, acc);
                acc = fmaf(wh[r][0].z, hv0.z, acc);
                acc = fmaf(wh[r][0].w, hv0.w, acc);
                acc = fmaf(wh[r][1].x, hv1.x, acc);
                acc = fmaf(wh[r][1].y, hv1.y, acc);
                acc = fmaf(wh[r][1].z, hv1.z, acc);
                acc = fmaf(wh[r][1].w, hv1.w, acc);
                a[r] = acc;
            }
            // cndmask-free butterfly reduce-scatter over 16 col-lanes
            float t0 = a[0] + dpp_movf<0xB1>(a[4]);
            float t1 = a[1] + dpp_movf<0xB1>(a[5]);
            float t2 = a[2] + dpp_movf<0xB1>(a[6]);
            float t3 = a[3] + dpp_movf<0xB1>(a[7]);
            float u0 = t0 + dpp_movf<0x4E>(t2);
            float u1 = t1 + dpp_movf<0x4E>(t3);
            u0 += dpp_movf<0x124>(u0);
            u1 += dpp_movf<0x124>(u1);
            u0 += dpp_movf<0x128>(u0);
            u1 += dpp_movf<0x128>(u1);

            if (cg < 4) {   // lanes cg>=4 hold duplicates
                float h0 = tanh_fast(u0 + xwp.x);
                float h1 = tanh_fast(u1 + xwp.y);
                *(float2*)&hbuf[cur ^ 1][hw] = make_float2(h0, h1);
            }

            // --- proj fmacs for chunk ch+1, col-slice s ---
            if (pf_proj) {
#pragma unroll
                for (int r = 0; r < 8; ++r) {
                    float acc = xacc[r];
                    acc = fmaf(pw0[r].x, pxv0.x, acc);
                    acc = fmaf(pw0[r].y, pxv0.y, acc);
                    acc = fmaf(pw0[r].z, pxv0.z, acc);
                    acc = fmaf(pw0[r].w, pxv0.w, acc);
                    acc = fmaf(pw1[r].x, pxv1.x, acc);
                    acc = fmaf(pw1[r].y, pxv1.y, acc);
                    acc = fmaf(pw1[r].z, pxv1.z, acc);
                    acc = fmaf(pw1[r].w, pxv1.w, acc);
                    xacc[r] = acc;
                }
            }

            if (s == CH - 1) {
                if (pf_proj) {
                    *(float4*)&xww[XSTR * sl + (rg << 3)] =
                        make_float4(xacc[0], xacc[1], xacc[2], xacc[3]);
                    *(float4*)&xww[XSTR * sl + (rg << 3) + 4] =
                        make_float4(xacc[4], xacc[5], xacc[6], xacc[7]);
#pragma unroll
                    for (int r = 0; r < 8; ++r) xacc[r] = bias[r];
                }
                if (pf_stage) {
                    float* nb = &xbuf[ch & 1][0];
                    *(float4*)&nb[dst0] = q0;
                    *(float4*)&nb[dst1] = q1;
                }
            }
            __syncthreads();
            cur ^= 1;
        }
    }
    // cur == 0 after 2048 toggles; hbuf[0] holds h_final (padded layout)
    if (t < HID) out[(size_t)b * HID + t] = hbuf[cur][t + ((t >> 3) << 2)];
}

extern "C" void kernel_launch(void* const* d_in, const int* in_sizes, int n_in,
                              void* d_out, int out_size, void* d_ws, size_t ws_size,
                              hipStream_t stream) {
    const float* x   = (const float*)d_in[0];
    const float* Wih = (const float*)d_in[1];
    const float* bih = (const float*)d_in[2];
    const float* Whh = (const float*)d_in[3];
    const float* bhh = (const float*)d_in[4];
    float* out = (float*)d_out;

    rnn_scan_kernel<<<BATCH, 256, 0, stream>>>(x, Wih, bih, Whh, bhh, out);
}